// Round 3
// baseline (2609.864 us; speedup 1.0000x reference)
//
#include <hip/hip_runtime.h>

// Problem constants
#define B_  8192
#define L_  10
#define D_  128
#define H_  64
#define OUT_ 5

// ws float layout (all fp32):
#define WS_ENCW4   0                    // 192*256: [k][l][q] = encW[j=q*64+l][k]  (k<128: Wih, else Whh)
#define WS_ENCB4   49152                // 256:     [l][q] = bih[j]+bhh[j]
#define WS_DECW4   49408                // 69*256:  [k][l][q] = decW[j][k] (k<5: Wih, else Whh)
#define WS_DECB4   67072                // 256
#define WS_W1HC2   67328                // 64*64*2: [e][l][{W1h[l][e], W1c[l][e]}]
#define WS_W1XT    75520                // 64*64:   [e][l] = W1x[l][e]

__device__ __forceinline__ float sigmf(float x){ return 1.f/(1.f+__expf(-x)); }
__device__ __forceinline__ float tanhf_(float x){ return 1.f - 2.f/(1.f+__expf(2.f*x)); }
__device__ __forceinline__ float bcast(float v, int lane){
  return __uint_as_float(__builtin_amdgcn_readlane(__float_as_uint(v), lane));
}

__global__ void prep_kernel(const float* __restrict__ encWih, const float* __restrict__ encWhh,
                            const float* __restrict__ encbih, const float* __restrict__ encbhh,
                            const float* __restrict__ decWih, const float* __restrict__ decWhh,
                            const float* __restrict__ decbih, const float* __restrict__ decbhh,
                            const float* __restrict__ w1, float* __restrict__ ws)
{
  int stride = gridDim.x * blockDim.x;
  int tid0 = blockIdx.x * blockDim.x + threadIdx.x;
  for (int idx = tid0; idx < 192*256; idx += stride) {
    int k = idx >> 8, r = idx & 255, l = r >> 2, q = r & 3;
    int j = q*64 + l;
    float v = (k < 128) ? encWih[j*128 + k] : encWhh[j*64 + (k-128)];
    ws[WS_ENCW4 + idx] = v;
  }
  for (int idx = tid0; idx < 256; idx += stride) {
    int l = idx >> 2, q = idx & 3, j = q*64+l;
    ws[WS_ENCB4+idx] = encbih[j] + encbhh[j];
  }
  for (int idx = tid0; idx < 69*256; idx += stride) {
    int k = idx >> 8, r = idx & 255, l = r >> 2, q = r & 3, j = q*64+l;
    float v = (k < 5) ? decWih[j*5 + k] : decWhh[j*64 + (k-5)];
    ws[WS_DECW4 + idx] = v;
  }
  for (int idx = tid0; idx < 256; idx += stride) {
    int l = idx >> 2, q = idx & 3, j = q*64+l;
    ws[WS_DECB4+idx] = decbih[j] + decbhh[j];
  }
  for (int idx = tid0; idx < 64*64; idx += stride) {
    int e = idx >> 6, l = idx & 63;
    ws[WS_W1HC2 + (e*64+l)*2 + 0] = w1[l*192 + e];
    ws[WS_W1HC2 + (e*64+l)*2 + 1] = w1[l*192 + 64 + e];
    ws[WS_W1XT  + idx]            = w1[l*192 + 128 + e];
  }
}

#define R 2   // batch rows per wave

// FMA block for one k-slice: broadcast source element (lane DD) for both rows,
// 4 gate quadrants each, written as float2 pairs to invite v_pk_fma_f32.
#define GFMA(W, DD) { \
    float u0 = bcast(s0v, (DD)); \
    float u1 = bcast(s1v, (DD)); \
    a01_0.x += u0*(W).x; a01_0.y += u0*(W).y; \
    a23_0.x += u0*(W).z; a23_0.y += u0*(W).w; \
    a01_1.x += u1*(W).x; a01_1.y += u1*(W).y; \
    a23_1.x += u1*(W).z; a23_1.y += u1*(W).w; }

// 64-k weight panel, double-buffered 4-wide register prefetch.
#define PANEL64(WPBASE) { \
    const float4* wp_ = (WPBASE); \
    float4 wa0=wp_[0*64+l], wa1=wp_[1*64+l], wa2=wp_[2*64+l], wa3=wp_[3*64+l]; \
    _Pragma("unroll") \
    for (int d=0; d<64; d+=8){ \
      float4 wb0=wp_[(d+4)*64+l], wb1=wp_[(d+5)*64+l], wb2=wp_[(d+6)*64+l], wb3=wp_[(d+7)*64+l]; \
      GFMA(wa0,d+0) GFMA(wa1,d+1) GFMA(wa2,d+2) GFMA(wa3,d+3) \
      if (d+8<64){ wa0=wp_[(d+8)*64+l]; wa1=wp_[(d+9)*64+l]; wa2=wp_[(d+10)*64+l]; wa3=wp_[(d+11)*64+l]; } \
      GFMA(wb0,d+4) GFMA(wb1,d+5) GFMA(wb2,d+6) GFMA(wb3,d+7) \
    } }

__global__ __launch_bounds__(256, 4) void darnn_kernel(
    const float* __restrict__ x, const float* __restrict__ y_hist,
    const float* __restrict__ h0e, const float* __restrict__ c0e,
    const float* __restrict__ h0d, const float* __restrict__ c0d,
    const float* __restrict__ enc_attn_w,
    const float* __restrict__ dec_attn_b1, const float* __restrict__ dec_attn_w2,
    const float* __restrict__ dec_attn_b2,
    const float* __restrict__ fc_w, const float* __restrict__ fc_b,
    const float* __restrict__ fcout_w, const float* __restrict__ fcout_b,
    const float* __restrict__ ws, float* __restrict__ out)
{
  __shared__ float xenc[4][R][L_][64];   // 20 KB, per-wave private slices
  const int wv = threadIdx.x >> 6;
  const int l  = threadIdx.x & 63;
  const int brow = blockIdx.x * (4*R) + wv*R;

  float h[R], c[R];
  #pragma unroll
  for (int r=0;r<R;++r){
    h[r]=h0e[(brow+r)*64+l];
    c[r]=c0e[(brow+r)*64+l];
  }

  // Encoder input attention: at = softmax_d(score_x) (h/c/bias terms cancel in softmax)
  float at0[R], at1[R];
  {
    float wxv[L_];
    #pragma unroll
    for (int t=0;t<L_;++t) wxv[t]=enc_attn_w[2*H_ + t];
    #pragma unroll
    for (int r=0;r<R;++r){
      const float* xb = x + (size_t)(brow+r)*(L_*D_);
      float s0=0.f,s1=0.f;
      #pragma unroll
      for (int t=0;t<L_;++t){
        s0 += xb[t*D_+l]*wxv[t];
        s1 += xb[t*D_+64+l]*wxv[t];
      }
      float m = fmaxf(s0,s1);
      for (int o=32;o;o>>=1) m = fmaxf(m, __shfl_xor(m,o));
      float e0=__expf(s0-m), e1=__expf(s1-m);
      float ss=e0+e1;
      for (int o=32;o;o>>=1) ss += __shfl_xor(ss,o);
      float inv = 1.f/ss;
      at0[r]=e0*inv; at1[r]=e1*inv;
    }
  }

  // ---------------- Encoder ----------------
  const float4* encP = (const float4*)(ws + WS_ENCW4);
  for (int t=0;t<L_;++t){
    float wi0[R], wi1[R];
    #pragma unroll
    for (int r=0;r<R;++r){
      const float* xb = x + (size_t)(brow+r)*(L_*D_) + t*D_;
      wi0[r]=at0[r]*xb[l];
      wi1[r]=at1[r]*xb[64+l];
    }
    float4 bs = *(const float4*)(ws + WS_ENCB4 + l*4);
    float2 a01_0 = make_float2(bs.x,bs.y), a23_0 = make_float2(bs.z,bs.w);
    float2 a01_1 = a01_0, a23_1 = a23_0;
    float s0v, s1v;
    s0v = wi0[0]; s1v = wi0[1];
    PANEL64(encP);
    s0v = wi1[0]; s1v = wi1[1];
    PANEL64(encP + 64*64);
    s0v = h[0];  s1v = h[1];
    PANEL64(encP + 128*64);
    {
      float ig=sigmf(a01_0.x), fg=sigmf(a01_0.y), gg=tanhf_(a23_0.x), og=sigmf(a23_0.y);
      c[0]=fg*c[0]+ig*gg; h[0]=og*tanhf_(c[0]); xenc[wv][0][t][l]=h[0];
    }
    {
      float ig=sigmf(a01_1.x), fg=sigmf(a01_1.y), gg=tanhf_(a23_1.x), og=sigmf(a23_1.y);
      c[1]=fg*c[1]+ig*gg; h[1]=og*tanhf_(c[1]); xenc[wv][1][t][l]=h[1];
    }
  }

  // pre[r][lt][l] = sum_e xenc[r][lt][e] * W1x[l][e]  (e-outer: weight loaded once per e)
  float pre[R][L_];
  {
    float xe[R][L_];
    #pragma unroll
    for (int r=0;r<R;++r)
      #pragma unroll
      for (int lt=0;lt<L_;++lt){ xe[r][lt]=xenc[wv][r][lt][l]; pre[r][lt]=0.f; }
    #pragma unroll 4
    for (int e=0;e<64;++e){
      float w = ws[WS_W1XT + e*64+l];
      #pragma unroll
      for (int r=0;r<R;++r)
        #pragma unroll
        for (int lt=0;lt<L_;++lt)
          pre[r][lt] += bcast(xe[r][lt], e) * w;
    }
  }

  // ---------------- Decoder ----------------
  #pragma unroll
  for (int r=0;r<R;++r){
    h[r]=h0d[(brow+r)*64+l];
    c[r]=c0d[(brow+r)*64+l];
  }
  float b1l = dec_attn_b1[l];
  float w2l = dec_attn_w2[l];
  float b2  = dec_attn_b2[0];
  float ctx[R];
  #pragma unroll
  for (int r=0;r<R;++r) ctx[r]=0.f;

  const float4* decP = (const float4*)(ws + WS_DECW4);
  const float2* vp   = (const float2*)(ws + WS_W1HC2);

  for (int t=0;t<L_;++t){
    // vb[l] = b1[l] + sum_e h[e] W1h[l][e] + c[e] W1c[l][e]
    float vb[R];
    #pragma unroll
    for (int r=0;r<R;++r) vb[r]=b1l;
    #pragma unroll 8
    for (int e=0;e<64;++e){
      float2 w = vp[e*64+l];
      vb[0] += bcast(h[0],e)*w.x + bcast(c[0],e)*w.y;
      vb[1] += bcast(h[1],e)*w.x + bcast(c[1],e)*w.y;
    }
    // scores -> softmax over L -> ctx, per row
    float yt[R][OUT_];
    #pragma unroll
    for (int r=0;r<R;++r){
      float sc[L_];
      #pragma unroll
      for (int lt=0;lt<L_;++lt){
        float z = tanhf_(pre[r][lt]+vb[r]);
        float p = z*w2l;
        for (int o=32;o;o>>=1) p += __shfl_xor(p,o);
        sc[lt]=p+b2;
      }
      float mx=sc[0];
      #pragma unroll
      for (int lt=1;lt<L_;++lt) mx=fmaxf(mx,sc[lt]);
      float ssum=0.f;
      #pragma unroll
      for (int lt=0;lt<L_;++lt){ sc[lt]=__expf(sc[lt]-mx); ssum+=sc[lt]; }
      float inv=1.f/ssum;
      float cx=0.f;
      #pragma unroll
      for (int lt=0;lt<L_;++lt) cx += sc[lt]*xenc[wv][r][lt][l];
      ctx[r]=cx*inv;
    }
    // y_tilde[o] = fc_b[o] + sum_e ctx[e] fc_w[o][e] + sum_j y_t[j] fc_w[o][64+j]
    #pragma unroll
    for (int r=0;r<R;++r){
      float yin[OUT_];
      #pragma unroll
      for (int j=0;j<OUT_;++j)
        yin[j]=y_hist[(size_t)(brow+r)*(L_*OUT_)+t*OUT_+j];
      #pragma unroll
      for (int o2=0;o2<OUT_;++o2){
        float p = ctx[r]*fc_w[o2*69+l];
        for (int o=32;o;o>>=1) p += __shfl_xor(p,o);
        p += fc_b[o2];
        #pragma unroll
        for (int j=0;j<OUT_;++j) p += yin[j]*fc_w[o2*69+64+j];
        yt[r][o2]=p;
      }
    }
    // gates
    float4 bs = *(const float4*)(ws + WS_DECB4 + l*4);
    float2 a01_0 = make_float2(bs.x,bs.y), a23_0 = make_float2(bs.z,bs.w);
    float2 a01_1 = a01_0, a23_1 = a23_0;
    #pragma unroll
    for (int k=0;k<OUT_;++k){
      float4 w = decP[k*64+l];
      float u0 = yt[0][k], u1 = yt[1][k];
      a01_0.x += u0*w.x; a01_0.y += u0*w.y; a23_0.x += u0*w.z; a23_0.y += u0*w.w;
      a01_1.x += u1*w.x; a01_1.y += u1*w.y; a23_1.x += u1*w.z; a23_1.y += u1*w.w;
    }
    {
      float s0v, s1v;
      s0v = h[0]; s1v = h[1];
      PANEL64(decP + 5*64);
    }
    {
      float ig=sigmf(a01_0.x), fg=sigmf(a01_0.y), gg=tanhf_(a23_0.x), og=sigmf(a23_0.y);
      c[0]=fg*c[0]+ig*gg; h[0]=og*tanhf_(c[0]);
    }
    {
      float ig=sigmf(a01_1.x), fg=sigmf(a01_1.y), gg=tanhf_(a23_1.x), og=sigmf(a23_1.y);
      c[1]=fg*c[1]+ig*gg; h[1]=og*tanhf_(c[1]);
    }
  }

  // out[b][o] = fcout_b[o] + sum_e h[e] fcout_w[o][e] + ctx[e] fcout_w[o][64+e]
  #pragma unroll
  for (int o2=0;o2<OUT_;++o2){
    float wa=fcout_w[o2*128+l];
    float wb=fcout_w[o2*128+64+l];
    float fb=fcout_b[o2];
    #pragma unroll
    for (int r=0;r<R;++r){
      float p = h[r]*wa + ctx[r]*wb;
      for (int o=32;o;o>>=1) p += __shfl_xor(p,o);
      if (l==o2) out[(size_t)(brow+r)*OUT_+o2] = p+fb;
    }
  }
}

extern "C" void kernel_launch(void* const* d_in, const int* in_sizes, int n_in,
                              void* d_out, int out_size, void* d_ws, size_t ws_size,
                              hipStream_t stream) {
  const float* x          = (const float*)d_in[0];
  const float* y_hist     = (const float*)d_in[1];
  const float* h0_enc     = (const float*)d_in[2];
  const float* c0_enc     = (const float*)d_in[3];
  const float* h0_dec     = (const float*)d_in[4];
  const float* c0_dec     = (const float*)d_in[5];
  const float* enc_attn_w = (const float*)d_in[6];
  const float* enc_Wih    = (const float*)d_in[8];
  const float* enc_Whh    = (const float*)d_in[9];
  const float* enc_bih    = (const float*)d_in[10];
  const float* enc_bhh    = (const float*)d_in[11];
  const float* dec_attn_w1= (const float*)d_in[12];
  const float* dec_attn_b1= (const float*)d_in[13];
  const float* dec_attn_w2= (const float*)d_in[14];
  const float* dec_attn_b2= (const float*)d_in[15];
  const float* dec_Wih    = (const float*)d_in[16];
  const float* dec_Whh    = (const float*)d_in[17];
  const float* dec_bih    = (const float*)d_in[18];
  const float* dec_bhh    = (const float*)d_in[19];
  const float* fc_w       = (const float*)d_in[20];
  const float* fc_b       = (const float*)d_in[21];
  const float* fcout_w    = (const float*)d_in[22];
  const float* fcout_b    = (const float*)d_in[23];
  float* ws = (float*)d_ws;
  float* out = (float*)d_out;

  hipLaunchKernelGGL(prep_kernel, dim3(128), dim3(256), 0, stream,
                     enc_Wih, enc_Whh, enc_bih, enc_bhh,
                     dec_Wih, dec_Whh, dec_bih, dec_bhh,
                     dec_attn_w1, ws);
  hipLaunchKernelGGL(darnn_kernel, dim3(B_/(4*R)), dim3(256), 0, stream,
                     x, y_hist, h0_enc, c0_enc, h0_dec, c0_dec,
                     enc_attn_w, dec_attn_b1, dec_attn_w2, dec_attn_b2,
                     fc_w, fc_b, fcout_w, fcout_b, ws, out);
}

// Round 4
// 625.183 us; speedup vs baseline: 4.1746x; 4.1746x over previous
//
#include <hip/hip_runtime.h>

// Problem constants
#define B_  8192
#define L_  10
#define D_  128
#define H_  64
#define OUT_ 5

// ws float layout (all fp32):
#define WS_ENCW4   0                    // 192*256: [k][l][q] = encW[j=q*64+l][k]  (k<128: Wih, else Whh)
#define WS_ENCB4   49152                // 256:     [l][q] = bih[j]+bhh[j]
#define WS_DECW4   49408                // 69*256:  [k][l][q] = decW[j][k] (k<5: Wih, else Whh)
#define WS_DECB4   67072                // 256
#define WS_W1HC2   67328                // 64*64*2: [e][l][{W1h[l][e], W1c[l][e]}]
#define WS_W1XT    75520                // 64*64:   [e][l] = W1x[l][e]

__device__ __forceinline__ float sigmf(float x){ return 1.f/(1.f+__expf(-x)); }
__device__ __forceinline__ float tanhf_(float x){ return 1.f - 2.f/(1.f+__expf(2.f*x)); }
__device__ __forceinline__ float bcast(float v, int lane){
  return __uint_as_float(__builtin_amdgcn_readlane(__float_as_uint(v), lane));
}

__global__ void prep_kernel(const float* __restrict__ encWih, const float* __restrict__ encWhh,
                            const float* __restrict__ encbih, const float* __restrict__ encbhh,
                            const float* __restrict__ decWih, const float* __restrict__ decWhh,
                            const float* __restrict__ decbih, const float* __restrict__ decbhh,
                            const float* __restrict__ w1, float* __restrict__ ws)
{
  int stride = gridDim.x * blockDim.x;
  int tid0 = blockIdx.x * blockDim.x + threadIdx.x;
  for (int idx = tid0; idx < 192*256; idx += stride) {
    int k = idx >> 8, r = idx & 255, l = r >> 2, q = r & 3;
    int j = q*64 + l;
    float v = (k < 128) ? encWih[j*128 + k] : encWhh[j*64 + (k-128)];
    ws[WS_ENCW4 + idx] = v;
  }
  for (int idx = tid0; idx < 256; idx += stride) {
    int l = idx >> 2, q = idx & 3, j = q*64+l;
    ws[WS_ENCB4+idx] = encbih[j] + encbhh[j];
  }
  for (int idx = tid0; idx < 69*256; idx += stride) {
    int k = idx >> 8, r = idx & 255, l = r >> 2, q = r & 3, j = q*64+l;
    float v = (k < 5) ? decWih[j*5 + k] : decWhh[j*64 + (k-5)];
    ws[WS_DECW4 + idx] = v;
  }
  for (int idx = tid0; idx < 256; idx += stride) {
    int l = idx >> 2, q = idx & 3, j = q*64+l;
    ws[WS_DECB4+idx] = decbih[j] + decbhh[j];
  }
  for (int idx = tid0; idx < 64*64; idx += stride) {
    int e = idx >> 6, l = idx & 63;
    ws[WS_W1HC2 + (e*64+l)*2 + 0] = w1[l*192 + e];
    ws[WS_W1HC2 + (e*64+l)*2 + 1] = w1[l*192 + 64 + e];
    ws[WS_W1XT  + idx]            = w1[l*192 + 128 + e];
  }
}

#define R 2   // batch rows per wave  (grid = 8192/(4*R) = 1024 blocks -> 4 blocks/CU resident)

__global__ __launch_bounds__(256, 2) void darnn_kernel(
    const float* __restrict__ x, const float* __restrict__ y_hist,
    const float* __restrict__ h0e, const float* __restrict__ c0e,
    const float* __restrict__ h0d, const float* __restrict__ c0d,
    const float* __restrict__ enc_attn_w,
    const float* __restrict__ dec_attn_b1, const float* __restrict__ dec_attn_w2,
    const float* __restrict__ dec_attn_b2,
    const float* __restrict__ fc_w, const float* __restrict__ fc_b,
    const float* __restrict__ fcout_w, const float* __restrict__ fcout_b,
    const float* __restrict__ ws, float* __restrict__ out)
{
  __shared__ float xenc[4][R][L_][64];   // 20 KB, per-wave private slices
  const int wv = threadIdx.x >> 6;
  const int l  = threadIdx.x & 63;
  const int brow = blockIdx.x * (4*R) + wv*R;

  const float* encW4 = ws + WS_ENCW4;
  const float* decW4 = ws + WS_DECW4;

  float h[R], c[R];
  #pragma unroll
  for (int r=0;r<R;++r){
    h[r]=h0e[(brow+r)*64+l];
    c[r]=c0e[(brow+r)*64+l];
  }

  // Encoder input attention: at = softmax_d(score_x) (h/c/bias terms cancel in softmax)
  float at0[R], at1[R];
  {
    float wxv[L_];
    #pragma unroll
    for (int t=0;t<L_;++t) wxv[t]=enc_attn_w[2*H_ + t];
    #pragma unroll
    for (int r=0;r<R;++r){
      const float* xb = x + (size_t)(brow+r)*(L_*D_);
      float s0=0.f,s1=0.f;
      #pragma unroll
      for (int t=0;t<L_;++t){
        s0 += xb[t*D_+l]*wxv[t];
        s1 += xb[t*D_+64+l]*wxv[t];
      }
      float m = fmaxf(s0,s1);
      for (int o=32;o;o>>=1) m = fmaxf(m, __shfl_xor(m,o));
      float e0=__expf(s0-m), e1=__expf(s1-m);
      float ss=e0+e1;
      for (int o=32;o;o>>=1) ss += __shfl_xor(ss,o);
      float inv = 1.f/ss;
      at0[r]=e0*inv; at1[r]=e1*inv;
    }
  }

  // ---------------- Encoder ----------------
  for (int t=0;t<L_;++t){
    float wi0[R], wi1[R];
    #pragma unroll
    for (int r=0;r<R;++r){
      const float* xb = x + (size_t)(brow+r)*(L_*D_) + t*D_;
      wi0[r]=at0[r]*xb[l];
      wi1[r]=at1[r]*xb[64+l];
    }
    float4 bs = *(const float4*)(ws + WS_ENCB4 + l*4);
    float a0[R],a1[R],a2[R],a3[R];
    #pragma unroll
    for (int r=0;r<R;++r){ a0[r]=bs.x;a1[r]=bs.y;a2[r]=bs.z;a3[r]=bs.w; }
    #pragma unroll 4
    for (int d=0; d<64; ++d){
      float4 w = *(const float4*)(encW4 + (d*64+l)*4);
      #pragma unroll
      for (int r=0;r<R;++r){
        float v = bcast(wi0[r], d);
        a0[r]+=v*w.x; a1[r]+=v*w.y; a2[r]+=v*w.z; a3[r]+=v*w.w;
      }
    }
    #pragma unroll 4
    for (int d=0; d<64; ++d){
      float4 w = *(const float4*)(encW4 + ((64+d)*64+l)*4);
      #pragma unroll
      for (int r=0;r<R;++r){
        float v = bcast(wi1[r], d);
        a0[r]+=v*w.x; a1[r]+=v*w.y; a2[r]+=v*w.z; a3[r]+=v*w.w;
      }
    }
    #pragma unroll 4
    for (int e=0;e<64;++e){
      float4 w = *(const float4*)(encW4 + ((128+e)*64+l)*4);
      #pragma unroll
      for (int r=0;r<R;++r){
        float v = bcast(h[r], e);
        a0[r]+=v*w.x; a1[r]+=v*w.y; a2[r]+=v*w.z; a3[r]+=v*w.w;
      }
    }
    #pragma unroll
    for (int r=0;r<R;++r){
      float ig=sigmf(a0[r]), fg=sigmf(a1[r]), gg=tanhf_(a2[r]), og=sigmf(a3[r]);
      c[r]=fg*c[r]+ig*gg;
      h[r]=og*tanhf_(c[r]);
      xenc[wv][r][t][l]=h[r];
    }
  }

  // pre[r][lt][l] = sum_e xenc[r][lt][e] * W1x[l][e]  (e-outer: weight loaded once per e)
  float pre[R][L_];
  #pragma unroll
  for (int r=0;r<R;++r)
    #pragma unroll
    for (int lt=0;lt<L_;++lt) pre[r][lt]=0.f;
  for (int lt=0; lt<L_; ++lt){
    float xe[R];
    #pragma unroll
    for (int r=0;r<R;++r) xe[r]=xenc[wv][r][lt][l];
    #pragma unroll 4
    for (int e=0;e<64;++e){
      float w = ws[WS_W1XT + e*64+l];
      #pragma unroll
      for (int r=0;r<R;++r) pre[r][lt] += bcast(xe[r], e) * w;
    }
  }

  // ---------------- Decoder ----------------
  #pragma unroll
  for (int r=0;r<R;++r){
    h[r]=h0d[(brow+r)*64+l];
    c[r]=c0d[(brow+r)*64+l];
  }
  float b1l = dec_attn_b1[l];
  float w2l = dec_attn_w2[l];
  float b2  = dec_attn_b2[0];
  float ctx[R];
  #pragma unroll
  for (int r=0;r<R;++r) ctx[r]=0.f;

  for (int t=0;t<L_;++t){
    // vb[l] = b1[l] + sum_e h[e] W1h[l][e] + c[e] W1c[l][e]
    float vb[R];
    #pragma unroll
    for (int r=0;r<R;++r) vb[r]=b1l;
    #pragma unroll 8
    for (int e=0;e<64;++e){
      float2 w = *(const float2*)(ws + WS_W1HC2 + (e*64+l)*2);
      #pragma unroll
      for (int r=0;r<R;++r)
        vb[r] += bcast(h[r],e)*w.x + bcast(c[r],e)*w.y;
    }
    // scores -> softmax over L -> ctx, per row
    float yt[R][OUT_];
    #pragma unroll
    for (int r=0;r<R;++r){
      float sc[L_];
      #pragma unroll
      for (int lt=0;lt<L_;++lt){
        float z = tanhf_(pre[r][lt]+vb[r]);
        float p = z*w2l;
        for (int o=32;o;o>>=1) p += __shfl_xor(p,o);
        sc[lt]=p+b2;
      }
      float mx=sc[0];
      #pragma unroll
      for (int lt=1;lt<L_;++lt) mx=fmaxf(mx,sc[lt]);
      float ssum=0.f;
      #pragma unroll
      for (int lt=0;lt<L_;++lt){ sc[lt]=__expf(sc[lt]-mx); ssum+=sc[lt]; }
      float inv=1.f/ssum;
      float cx=0.f;
      #pragma unroll
      for (int lt=0;lt<L_;++lt) cx += sc[lt]*xenc[wv][r][lt][l];
      ctx[r]=cx*inv;
    }
    // y_tilde[o] = fc_b[o] + sum_e ctx[e] fc_w[o][e] + sum_j y_t[j] fc_w[o][64+j]
    #pragma unroll
    for (int r=0;r<R;++r){
      float yin[OUT_];
      #pragma unroll
      for (int j=0;j<OUT_;++j)
        yin[j]=y_hist[(size_t)(brow+r)*(L_*OUT_)+t*OUT_+j];
      #pragma unroll
      for (int o2=0;o2<OUT_;++o2){
        float p = ctx[r]*fc_w[o2*69+l];
        for (int o=32;o;o>>=1) p += __shfl_xor(p,o);
        p += fc_b[o2];
        #pragma unroll
        for (int j=0;j<OUT_;++j) p += yin[j]*fc_w[o2*69+64+j];
        yt[r][o2]=p;
      }
    }
    // gates
    float4 bs = *(const float4*)(ws + WS_DECB4 + l*4);
    float a0[R],a1[R],a2[R],a3[R];
    #pragma unroll
    for (int r=0;r<R;++r){ a0[r]=bs.x;a1[r]=bs.y;a2[r]=bs.z;a3[r]=bs.w; }
    #pragma unroll
    for (int k=0;k<OUT_;++k){
      float4 w = *(const float4*)(decW4 + (k*64+l)*4);
      #pragma unroll
      for (int r=0;r<R;++r){
        float v = yt[r][k];
        a0[r]+=v*w.x;a1[r]+=v*w.y;a2[r]+=v*w.z;a3[r]+=v*w.w;
      }
    }
    #pragma unroll 4
    for (int e=0;e<64;++e){
      float4 w = *(const float4*)(decW4 + ((5+e)*64+l)*4);
      #pragma unroll
      for (int r=0;r<R;++r){
        float v = bcast(h[r],e);
        a0[r]+=v*w.x;a1[r]+=v*w.y;a2[r]+=v*w.z;a3[r]+=v*w.w;
      }
    }
    #pragma unroll
    for (int r=0;r<R;++r){
      float ig=sigmf(a0[r]), fg=sigmf(a1[r]), gg=tanhf_(a2[r]), og=sigmf(a3[r]);
      c[r]=fg*c[r]+ig*gg;
      h[r]=og*tanhf_(c[r]);
    }
  }

  // out[b][o] = fcout_b[o] + sum_e h[e] fcout_w[o][e] + ctx[e] fcout_w[o][64+e]
  #pragma unroll
  for (int o2=0;o2<OUT_;++o2){
    float wa=fcout_w[o2*128+l];
    float wb=fcout_w[o2*128+64+l];
    float fb=fcout_b[o2];
    #pragma unroll
    for (int r=0;r<R;++r){
      float p = h[r]*wa + ctx[r]*wb;
      for (int o=32;o;o>>=1) p += __shfl_xor(p,o);
      if (l==o2) out[(size_t)(brow+r)*OUT_+o2] = p+fb;
    }
  }
}

extern "C" void kernel_launch(void* const* d_in, const int* in_sizes, int n_in,
                              void* d_out, int out_size, void* d_ws, size_t ws_size,
                              hipStream_t stream) {
  const float* x          = (const float*)d_in[0];
  const float* y_hist     = (const float*)d_in[1];
  const float* h0_enc     = (const float*)d_in[2];
  const float* c0_enc     = (const float*)d_in[3];
  const float* h0_dec     = (const float*)d_in[4];
  const float* c0_dec     = (const float*)d_in[5];
  const float* enc_attn_w = (const float*)d_in[6];
  const float* enc_Wih    = (const float*)d_in[8];
  const float* enc_Whh    = (const float*)d_in[9];
  const float* enc_bih    = (const float*)d_in[10];
  const float* enc_bhh    = (const float*)d_in[11];
  const float* dec_attn_w1= (const float*)d_in[12];
  const float* dec_attn_b1= (const float*)d_in[13];
  const float* dec_attn_w2= (const float*)d_in[14];
  const float* dec_attn_b2= (const float*)d_in[15];
  const float* dec_Wih    = (const float*)d_in[16];
  const float* dec_Whh    = (const float*)d_in[17];
  const float* dec_bih    = (const float*)d_in[18];
  const float* dec_bhh    = (const float*)d_in[19];
  const float* fc_w       = (const float*)d_in[20];
  const float* fc_b       = (const float*)d_in[21];
  const float* fcout_w    = (const float*)d_in[22];
  const float* fcout_b    = (const float*)d_in[23];
  float* ws = (float*)d_ws;
  float* out = (float*)d_out;

  hipLaunchKernelGGL(prep_kernel, dim3(128), dim3(256), 0, stream,
                     enc_Wih, enc_Whh, enc_bih, enc_bhh,
                     dec_Wih, dec_Whh, dec_bih, dec_bhh,
                     dec_attn_w1, ws);
  hipLaunchKernelGGL(darnn_kernel, dim3(B_/(4*R)), dim3(256), 0, stream,
                     x, y_hist, h0_enc, c0_enc, h0_dec, c0_dec,
                     enc_attn_w, dec_attn_b1, dec_attn_w2, dec_attn_b2,
                     fc_w, fc_b, fcout_w, fcout_b, ws, out);
}

// Round 5
// 617.084 us; speedup vs baseline: 4.2294x; 1.0131x over previous
//
#include <hip/hip_runtime.h>

// Problem constants
#define B_  8192
#define L_  10
#define D_  128
#define H_  64
#define OUT_ 5

// ws float layout (all fp32):
#define WS_ENCW4   0                    // 192*256: [k][l][q] = encW[j=q*64+l][k]  (k<128: Wih, else Whh)
#define WS_ENCB4   49152                // 256:     [l][q] = bih[j]+bhh[j]
#define WS_DECW4   49408                // 69*256:  [k][l][q] = decW[j][k] (k<5: Wih, else Whh)
#define WS_DECB4   67072                // 256
#define WS_W1HC2   67328                // 64*64*2: [e][l][{W1h[l][e], W1c[l][e]}]
#define WS_W1XT    75520                // 64*64:   [e][l] = W1x[l][e]

__device__ __forceinline__ float sigmf(float x){ return 1.f/(1.f+__expf(-x)); }
__device__ __forceinline__ float tanhf_(float x){ return 1.f - 2.f/(1.f+__expf(2.f*x)); }
__device__ __forceinline__ float bcast(float v, int lane){
  return __uint_as_float(__builtin_amdgcn_readlane(__float_as_uint(v), lane));
}

__global__ void prep_kernel(const float* __restrict__ encWih, const float* __restrict__ encWhh,
                            const float* __restrict__ encbih, const float* __restrict__ encbhh,
                            const float* __restrict__ decWih, const float* __restrict__ decWhh,
                            const float* __restrict__ decbih, const float* __restrict__ decbhh,
                            const float* __restrict__ w1, float* __restrict__ ws)
{
  int stride = gridDim.x * blockDim.x;
  int tid0 = blockIdx.x * blockDim.x + threadIdx.x;
  for (int idx = tid0; idx < 192*256; idx += stride) {
    int k = idx >> 8, r = idx & 255, l = r >> 2, q = r & 3;
    int j = q*64 + l;
    float v = (k < 128) ? encWih[j*128 + k] : encWhh[j*64 + (k-128)];
    ws[WS_ENCW4 + idx] = v;
  }
  for (int idx = tid0; idx < 256; idx += stride) {
    int l = idx >> 2, q = idx & 3, j = q*64+l;
    ws[WS_ENCB4+idx] = encbih[j] + encbhh[j];
  }
  for (int idx = tid0; idx < 69*256; idx += stride) {
    int k = idx >> 8, r = idx & 255, l = r >> 2, q = r & 3, j = q*64+l;
    float v = (k < 5) ? decWih[j*5 + k] : decWhh[j*64 + (k-5)];
    ws[WS_DECW4 + idx] = v;
  }
  for (int idx = tid0; idx < 256; idx += stride) {
    int l = idx >> 2, q = idx & 3, j = q*64+l;
    ws[WS_DECB4+idx] = decbih[j] + decbhh[j];
  }
  for (int idx = tid0; idx < 64*64; idx += stride) {
    int e = idx >> 6, l = idx & 63;
    ws[WS_W1HC2 + (e*64+l)*2 + 0] = w1[l*192 + e];
    ws[WS_W1HC2 + (e*64+l)*2 + 1] = w1[l*192 + 64 + e];
    ws[WS_W1XT  + idx]            = w1[l*192 + 128 + e];
  }
}

#define R 2   // batch rows per wave  (grid = 8192/(4*R) = 1024 blocks -> 4 blocks/CU)

__global__ __launch_bounds__(256, 2) void darnn_kernel(
    const float* __restrict__ x, const float* __restrict__ y_hist,
    const float* __restrict__ h0e, const float* __restrict__ c0e,
    const float* __restrict__ h0d, const float* __restrict__ c0d,
    const float* __restrict__ enc_attn_w,
    const float* __restrict__ dec_attn_b1, const float* __restrict__ dec_attn_w2,
    const float* __restrict__ dec_attn_b2,
    const float* __restrict__ fc_w, const float* __restrict__ fc_b,
    const float* __restrict__ fcout_w, const float* __restrict__ fcout_b,
    const float* __restrict__ ws, float* __restrict__ out)
{
  // NO __shared__: encoder outputs live in registers (xe[r][t]); cross-element
  // access goes through readlane broadcasts, which we use everywhere anyway.
  const int l  = threadIdx.x & 63;
  const int wv = threadIdx.x >> 6;
  const int brow = blockIdx.x * (4*R) + wv*R;

  const float* encW4 = ws + WS_ENCW4;
  const float* decW4 = ws + WS_DECW4;

  float h[R], c[R];
  #pragma unroll
  for (int r=0;r<R;++r){
    h[r]=h0e[(brow+r)*64+l];
    c[r]=c0e[(brow+r)*64+l];
  }

  // Encoder input attention: at = softmax_d(score_x) (h/c/bias terms cancel in softmax)
  float at0[R], at1[R];
  {
    float wxv[L_];
    #pragma unroll
    for (int t=0;t<L_;++t) wxv[t]=enc_attn_w[2*H_ + t];
    #pragma unroll
    for (int r=0;r<R;++r){
      const float* xb = x + (size_t)(brow+r)*(L_*D_);
      float s0=0.f,s1=0.f;
      #pragma unroll
      for (int t=0;t<L_;++t){
        s0 += xb[t*D_+l]*wxv[t];
        s1 += xb[t*D_+64+l]*wxv[t];
      }
      float m = fmaxf(s0,s1);
      for (int o=32;o;o>>=1) m = fmaxf(m, __shfl_xor(m,o));
      float e0=__expf(s0-m), e1=__expf(s1-m);
      float ss=e0+e1;
      for (int o=32;o;o>>=1) ss += __shfl_xor(ss,o);
      float inv = 1.f/ss;
      at0[r]=e0*inv; at1[r]=e1*inv;
    }
  }

  // ---------------- Encoder ----------------
  float xe[R][L_];          // encoder hidden states, lane l holds element l
  const float* xb0 = x + (size_t)(brow+0)*(L_*D_);
  const float* xb1 = x + (size_t)(brow+1)*(L_*D_);
  float4 encbs = *(const float4*)(ws + WS_ENCB4 + l*4);

  // prefetch t=0 input
  float nx0a = xb0[l], nx0b = xb0[64+l];
  float nx1a = xb1[l], nx1b = xb1[64+l];

  for (int t=0;t<L_;++t){
    float wi0[R], wi1[R];
    wi0[0]=at0[0]*nx0a; wi1[0]=at1[0]*nx0b;
    wi0[1]=at0[1]*nx1a; wi1[1]=at1[1]*nx1b;
    // prefetch next t's input while panels compute
    if (t+1 < L_){
      nx0a = xb0[(t+1)*D_+l]; nx0b = xb0[(t+1)*D_+64+l];
      nx1a = xb1[(t+1)*D_+l]; nx1b = xb1[(t+1)*D_+64+l];
    }
    float a0[R],a1[R],a2[R],a3[R];
    #pragma unroll
    for (int r=0;r<R;++r){ a0[r]=encbs.x;a1[r]=encbs.y;a2[r]=encbs.z;a3[r]=encbs.w; }
    #pragma unroll 4
    for (int d=0; d<64; ++d){
      float4 w = *(const float4*)(encW4 + (d*64+l)*4);
      #pragma unroll
      for (int r=0;r<R;++r){
        float v = bcast(wi0[r], d);
        a0[r]+=v*w.x; a1[r]+=v*w.y; a2[r]+=v*w.z; a3[r]+=v*w.w;
      }
    }
    #pragma unroll 4
    for (int d=0; d<64; ++d){
      float4 w = *(const float4*)(encW4 + ((64+d)*64+l)*4);
      #pragma unroll
      for (int r=0;r<R;++r){
        float v = bcast(wi1[r], d);
        a0[r]+=v*w.x; a1[r]+=v*w.y; a2[r]+=v*w.z; a3[r]+=v*w.w;
      }
    }
    #pragma unroll 4
    for (int e=0;e<64;++e){
      float4 w = *(const float4*)(encW4 + ((128+e)*64+l)*4);
      #pragma unroll
      for (int r=0;r<R;++r){
        float v = bcast(h[r], e);
        a0[r]+=v*w.x; a1[r]+=v*w.y; a2[r]+=v*w.z; a3[r]+=v*w.w;
      }
    }
    #pragma unroll
    for (int r=0;r<R;++r){
      float ig=sigmf(a0[r]), fg=sigmf(a1[r]), gg=tanhf_(a2[r]), og=sigmf(a3[r]);
      c[r]=fg*c[r]+ig*gg;
      h[r]=og*tanhf_(c[r]);
      xe[r][t]=h[r];
    }
  }

  // pre[r][lt][l] = sum_e xe[r][lt](e) * W1x[l][e]   (e-outer, weight loaded once per e)
  float pre[R][L_];
  #pragma unroll
  for (int r=0;r<R;++r)
    #pragma unroll
    for (int lt=0;lt<L_;++lt) pre[r][lt]=0.f;
  #pragma unroll 2
  for (int e=0;e<64;++e){
    float w = ws[WS_W1XT + e*64+l];
    #pragma unroll
    for (int r=0;r<R;++r)
      #pragma unroll
      for (int lt=0;lt<L_;++lt)
        pre[r][lt] += bcast(xe[r][lt], e) * w;
  }

  // ---------------- Decoder ----------------
  #pragma unroll
  for (int r=0;r<R;++r){
    h[r]=h0d[(brow+r)*64+l];
    c[r]=c0d[(brow+r)*64+l];
  }
  float b1l = dec_attn_b1[l];
  float w2l = dec_attn_w2[l];
  float b2  = dec_attn_b2[0];
  float4 decbs = *(const float4*)(ws + WS_DECB4 + l*4);
  // hoist fc weights: per-lane head part + uniform tail part
  float fcwl[OUT_], fcbv[OUT_], fcwt[OUT_][OUT_];
  #pragma unroll
  for (int o2=0;o2<OUT_;++o2){
    fcwl[o2]=fc_w[o2*69+l];
    fcbv[o2]=fc_b[o2];
    #pragma unroll
    for (int j=0;j<OUT_;++j) fcwt[o2][j]=fc_w[o2*69+64+j];
  }
  float ctx[R];
  #pragma unroll
  for (int r=0;r<R;++r) ctx[r]=0.f;

  const float* yb0 = y_hist + (size_t)(brow+0)*(L_*OUT_);
  const float* yb1 = y_hist + (size_t)(brow+1)*(L_*OUT_);

  for (int t=0;t<L_;++t){
    // prefetch y_t early (used after vb/softmax)
    float yin[R][OUT_];
    #pragma unroll
    for (int j=0;j<OUT_;++j){ yin[0][j]=yb0[t*OUT_+j]; yin[1][j]=yb1[t*OUT_+j]; }

    // vb[l] = b1[l] + sum_e h[e] W1h[l][e] + c[e] W1c[l][e]
    float vb[R];
    #pragma unroll
    for (int r=0;r<R;++r) vb[r]=b1l;
    #pragma unroll 8
    for (int e=0;e<64;++e){
      float2 w = *(const float2*)(ws + WS_W1HC2 + (e*64+l)*2);
      #pragma unroll
      for (int r=0;r<R;++r)
        vb[r] += bcast(h[r],e)*w.x + bcast(c[r],e)*w.y;
    }
    // scores -> softmax over L -> ctx, per row
    float yt[R][OUT_];
    #pragma unroll
    for (int r=0;r<R;++r){
      float sc[L_];
      #pragma unroll
      for (int lt=0;lt<L_;++lt){
        float z = tanhf_(pre[r][lt]+vb[r]);
        float p = z*w2l;
        for (int o=32;o;o>>=1) p += __shfl_xor(p,o);
        sc[lt]=p+b2;
      }
      float mx=sc[0];
      #pragma unroll
      for (int lt=1;lt<L_;++lt) mx=fmaxf(mx,sc[lt]);
      float ssum=0.f;
      #pragma unroll
      for (int lt=0;lt<L_;++lt){ sc[lt]=__expf(sc[lt]-mx); ssum+=sc[lt]; }
      float inv=1.f/ssum;
      float cx=0.f;
      #pragma unroll
      for (int lt=0;lt<L_;++lt) cx += sc[lt]*xe[r][lt];
      ctx[r]=cx*inv;
    }
    // y_tilde[o] = fc_b[o] + sum_e ctx[e] fc_w[o][e] + sum_j y_t[j] fc_w[o][64+j]
    #pragma unroll
    for (int r=0;r<R;++r){
      #pragma unroll
      for (int o2=0;o2<OUT_;++o2){
        float p = ctx[r]*fcwl[o2];
        for (int o=32;o;o>>=1) p += __shfl_xor(p,o);
        p += fcbv[o2];
        #pragma unroll
        for (int j=0;j<OUT_;++j) p += yin[r][j]*fcwt[o2][j];
        yt[r][o2]=p;
      }
    }
    // gates
    float a0[R],a1[R],a2[R],a3[R];
    #pragma unroll
    for (int r=0;r<R;++r){ a0[r]=decbs.x;a1[r]=decbs.y;a2[r]=decbs.z;a3[r]=decbs.w; }
    #pragma unroll
    for (int k=0;k<OUT_;++k){
      float4 w = *(const float4*)(decW4 + (k*64+l)*4);
      #pragma unroll
      for (int r=0;r<R;++r){
        float v = yt[r][k];
        a0[r]+=v*w.x;a1[r]+=v*w.y;a2[r]+=v*w.z;a3[r]+=v*w.w;
      }
    }
    #pragma unroll 4
    for (int e=0;e<64;++e){
      float4 w = *(const float4*)(decW4 + ((5+e)*64+l)*4);
      #pragma unroll
      for (int r=0;r<R;++r){
        float v = bcast(h[r],e);
        a0[r]+=v*w.x;a1[r]+=v*w.y;a2[r]+=v*w.z;a3[r]+=v*w.w;
      }
    }
    #pragma unroll
    for (int r=0;r<R;++r){
      float ig=sigmf(a0[r]), fg=sigmf(a1[r]), gg=tanhf_(a2[r]), og=sigmf(a3[r]);
      c[r]=fg*c[r]+ig*gg;
      h[r]=og*tanhf_(c[r]);
    }
  }

  // out[b][o] = fcout_b[o] + sum_e h[e] fcout_w[o][e] + ctx[e] fcout_w[o][64+e]
  #pragma unroll
  for (int o2=0;o2<OUT_;++o2){
    float wa=fcout_w[o2*128+l];
    float wb=fcout_w[o2*128+64+l];
    float fb=fcout_b[o2];
    #pragma unroll
    for (int r=0;r<R;++r){
      float p = h[r]*wa + ctx[r]*wb;
      for (int o=32;o;o>>=1) p += __shfl_xor(p,o);
      if (l==o2) out[(size_t)(brow+r)*OUT_+o2] = p+fb;
    }
  }
}

extern "C" void kernel_launch(void* const* d_in, const int* in_sizes, int n_in,
                              void* d_out, int out_size, void* d_ws, size_t ws_size,
                              hipStream_t stream) {
  const float* x          = (const float*)d_in[0];
  const float* y_hist     = (const float*)d_in[1];
  const float* h0_enc     = (const float*)d_in[2];
  const float* c0_enc     = (const float*)d_in[3];
  const float* h0_dec     = (const float*)d_in[4];
  const float* c0_dec     = (const float*)d_in[5];
  const float* enc_attn_w = (const float*)d_in[6];
  const float* enc_Wih    = (const float*)d_in[8];
  const float* enc_Whh    = (const float*)d_in[9];
  const float* enc_bih    = (const float*)d_in[10];
  const float* enc_bhh    = (const float*)d_in[11];
  const float* dec_attn_w1= (const float*)d_in[12];
  const float* dec_attn_b1= (const float*)d_in[13];
  const float* dec_attn_w2= (const float*)d_in[14];
  const float* dec_attn_b2= (const float*)d_in[15];
  const float* dec_Wih    = (const float*)d_in[16];
  const float* dec_Whh    = (const float*)d_in[17];
  const float* dec_bih    = (const float*)d_in[18];
  const float* dec_bhh    = (const float*)d_in[19];
  const float* fc_w       = (const float*)d_in[20];
  const float* fc_b       = (const float*)d_in[21];
  const float* fcout_w    = (const float*)d_in[22];
  const float* fcout_b    = (const float*)d_in[23];
  float* ws = (float*)d_ws;
  float* out = (float*)d_out;

  hipLaunchKernelGGL(prep_kernel, dim3(128), dim3(256), 0, stream,
                     enc_Wih, enc_Whh, enc_bih, enc_bhh,
                     dec_Wih, dec_Whh, dec_bih, dec_bhh,
                     dec_attn_w1, ws);
  hipLaunchKernelGGL(darnn_kernel, dim3(B_/(4*R)), dim3(256), 0, stream,
                     x, y_hist, h0_enc, c0_enc, h0_dec, c0_dec,
                     enc_attn_w, dec_attn_b1, dec_attn_w2, dec_attn_b2,
                     fc_w, fc_b, fcout_w, fcout_b, ws, out);
}